// Round 1
// baseline (346.897 us; speedup 1.0000x reference)
//
#include <hip/hip_runtime.h>
#include <hip/hip_bf16.h>
#include <stdint.h>

#define NN 8192
#define CC 256

typedef float f32x4 __attribute__((ext_vector_type(4)));
typedef short s16x8 __attribute__((ext_vector_type(8)));

// ---- workspace layout (float offsets). Total ~46.6 MB required. ----
#define OFF_WT  0                         // 256*256 transposed w_reduce
#define OFF_R   65536                     // N*C fp32 r
#define OFF_S   (OFF_R + NN*CC)           // N fp32 s
#define OFF_C0  (OFF_S + NN)              // 1 fp32 c0 (padded 16)
#define OFF_SS  (OFF_C0 + 16)             // 4*N fp32 partial row-sums of Z
#define OFF_V   (OFF_SS + 4*NN)           // 4*N*C fp32 partial Z@r
#define OFF_RB  (OFF_V + 4*NN*CC)         // N*C bf16 (as ushort) swizzled r

// ---------------- kernel 1: transpose Wr + compute c0 ----------------
__global__ __launch_bounds__(256) void k_prep(const float* __restrict__ w,
                                              const float* __restrict__ br,
                                              const float* __restrict__ wcv,
                                              const float* __restrict__ bc,
                                              float* __restrict__ ws) {
  int k = blockIdx.x, c = threadIdx.x;
  ws[OFF_WT + k * CC + c] = w[c * CC + k];   // wT[k][c] = w[c][k]
  if (blockIdx.x == 0 && threadIdx.x < 64) {
    int lane = threadIdx.x;
    f32x4 b4 = *(const f32x4*)&br[lane * 4];
    f32x4 w4 = *(const f32x4*)&wcv[lane * 4];
    float d = b4[0]*w4[0] + b4[1]*w4[1] + b4[2]*w4[2] + b4[3]*w4[3];
    #pragma unroll
    for (int m = 32; m >= 1; m >>= 1) d += __shfl_xor(d, m, 64);
    if (lane == 0) ws[OFF_C0] = d + bc[0];
  }
}

// ---------------- kernel 2: r = x @ Wr^T (fp32) + rb (bf16, B-frag order) ----
__global__ __launch_bounds__(256) void k_r(const float* __restrict__ x,
                                           float* __restrict__ ws) {
  __shared__ float xs[32][260];            // pad to kill 4-way bank conflict
  int bi = blockIdx.x;                      // 1024 blocks
  int rowblk = bi >> 2, colblk = bi & 3;    // 32 rows x 64 cols per block
  int tid = threadIdx.x;
  int i0 = rowblk * 32;
  for (int t = tid; t < 32 * 64; t += 256) {
    int rr = t >> 6, c4 = t & 63;
    *(f32x4*)&xs[rr][c4 * 4] = *(const f32x4*)&x[(i0 + rr) * CC + c4 * 4];
  }
  __syncthreads();
  int tx = tid & 15, ty = tid >> 4;
  int cbase = colblk * 64 + tx * 4;
  float acc[2][4] = {};
  const float* wt = ws + OFF_WT;
  for (int k = 0; k < CC; k++) {
    f32x4 wv = *(const f32x4*)&wt[k * CC + cbase];
    float x0 = xs[ty * 2 + 0][k];
    float x1 = xs[ty * 2 + 1][k];
    #pragma unroll
    for (int cc = 0; cc < 4; cc++) {
      acc[0][cc] = fmaf(x0, wv[cc], acc[0][cc]);
      acc[1][cc] = fmaf(x1, wv[cc], acc[1][cc]);
    }
  }
  unsigned short* rb = (unsigned short*)(ws + OFF_RB);
  #pragma unroll
  for (int rr = 0; rr < 2; rr++) {
    int j = i0 + ty * 2 + rr;
    f32x4 o = {acc[rr][0], acc[rr][1], acc[rr][2], acc[rr][3]};
    *(f32x4*)&ws[OFF_R + j * CC + cbase] = o;
    #pragma unroll
    for (int cc = 0; cc < 4; cc++) {
      int c = cbase + cc;
      unsigned u = __float_as_uint(acc[rr][cc]);
      u = (u + 0x7fffu + ((u >> 16) & 1u)) >> 16;   // RNE to bf16
      // B-fragment order: lane l=(kk>>3)*16+(c&15) holds k-run t=kk&7 of chunk J
      int idx = (((j >> 5) * 16 + (c >> 4)) * 64 + ((j >> 3) & 3) * 16 + (c & 15)) * 8 + (j & 7);
      rb[idx] = (unsigned short)u;
    }
  }
}

// ---------------- kernel 3: s = r @ wc (wave per row) ----------------
__global__ __launch_bounds__(256) void k_s(const float* __restrict__ wcv,
                                           float* __restrict__ ws) {
  int tid = threadIdx.x;
  int lane = tid & 63;
  int row = blockIdx.x * 4 + (tid >> 6);
  f32x4 rv = *(const f32x4*)&ws[OFF_R + row * CC + lane * 4];
  f32x4 wv = *(const f32x4*)&wcv[lane * 4];
  float d = rv[0]*wv[0] + rv[1]*wv[1] + rv[2]*wv[2] + rv[3]*wv[3];
  #pragma unroll
  for (int m = 32; m >= 1; m >>= 1) d += __shfl_xor(d, m, 64);
  if (lane == 0) ws[OFF_S + row] = d;
}

// ---------------- kernel 4: main pairwise flash-style kernel ----------------
// 512 blocks = 128 row-tiles (64 rows) x 4 j-splits (2048 j each), 4 waves/block.
__global__ __launch_bounds__(256) void k_main(float* __restrict__ ws) {
  int blk = blockIdx.x;
  int rt = blk >> 2, h = blk & 3;
  int tid = threadIdx.x;
  int w = tid >> 6, l = tid & 63;
  int lr = l & 15, g = l >> 4;
  int iw = rt * 64 + w * 16;                 // this wave's 16-row strip
  float c0v = ws[OFF_C0];
  float si = ws[OFF_S + iw + lr];
  float a = si + c0v;                        // sigmoid(a + s_j)
  f32x4 acc[16];
  #pragma unroll
  for (int i = 0; i < 16; i++) acc[i] = (f32x4)(0.f);
  float ssum = 0.f;
  const s16x8* rbs = (const s16x8*)(ws + OFF_RB);
  const float* sarr = ws + OFF_S;
  int j0 = h * 2048;
  for (int jb = j0; jb < j0 + 2048; jb += 32) {
    const float* sp = sarr + jb + g * 8;
    f32x4 sj0 = *(const f32x4*)sp;
    f32x4 sj1 = *(const f32x4*)(sp + 4);
    float z[8];
    #pragma unroll
    for (int t = 0; t < 8; t++) {
      float sj = (t < 4) ? sj0[t] : sj1[t - 4];
      float e = __expf(-(a + sj));
      float zz = __builtin_amdgcn_rcpf(1.0f + e);
      z[t] = zz;
      ssum += zz;
    }
    s16x8 af;
    #pragma unroll
    for (int t = 0; t < 8; t++) {
      unsigned u = __float_as_uint(z[t]);
      u = (u + 0x7fffu + ((u >> 16) & 1u)) >> 16;  // RNE to bf16
      af[t] = (short)u;
    }
    int Jbase = (jb >> 5) * 16;
    #pragma unroll
    for (int ct = 0; ct < 16; ct++) {
      s16x8 bf = rbs[((Jbase + ct) << 6) + l];
      acc[ct] = __builtin_amdgcn_mfma_f32_16x16x32_bf16(af, bf, acc[ct], 0, 0, 0);
    }
  }
  // row-sums of Z: lanes {l, l+16, l+32, l+48} share row lr
  ssum += __shfl_xor(ssum, 16, 64);
  ssum += __shfl_xor(ssum, 32, 64);
  if (l < 16) ws[OFF_SS + h * NN + iw + l] = ssum;
  // C/D layout: col = lane&15, row = (lane>>4)*4 + reg  [measured m89/m91]
  float* Vp = ws + OFF_V + h * (NN * CC);
  #pragma unroll
  for (int ct = 0; ct < 16; ct++) {
    #pragma unroll
    for (int q = 0; q < 4; q++) {
      Vp[(iw + g * 4 + q) * CC + ct * 16 + lr] = acc[ct][q];
    }
  }
}

// ---------------- kernel 5: epilogue out = (r+b)*S/N + V/N ----------------
__global__ __launch_bounds__(256) void k_epi(const float* __restrict__ br,
                                             const float* __restrict__ ws,
                                             float* __restrict__ out) {
  int idx = blockIdx.x * 256 + threadIdx.x;   // 524288 float4 units
  int i = idx >> 6, c4 = (idx & 63) * 4;
  float S = ws[OFF_SS + i] + ws[OFF_SS + NN + i] + ws[OFF_SS + 2 * NN + i] + ws[OFF_SS + 3 * NN + i];
  float m = S * (1.0f / NN);
  f32x4 rv = *(const f32x4*)&ws[OFF_R + i * CC + c4];
  f32x4 bv = *(const f32x4*)&br[c4];
  f32x4 v0 = *(const f32x4*)&ws[OFF_V + 0 * NN * CC + i * CC + c4];
  f32x4 v1 = *(const f32x4*)&ws[OFF_V + 1 * NN * CC + i * CC + c4];
  f32x4 v2 = *(const f32x4*)&ws[OFF_V + 2 * NN * CC + i * CC + c4];
  f32x4 v3 = *(const f32x4*)&ws[OFF_V + 3 * NN * CC + i * CC + c4];
  f32x4 o;
  #pragma unroll
  for (int t = 0; t < 4; t++)
    o[t] = (rv[t] + bv[t]) * m + (v0[t] + v1[t] + v2[t] + v3[t]) * (1.0f / NN);
  *(f32x4*)&out[i * CC + c4] = o;
}

extern "C" void kernel_launch(void* const* d_in, const int* in_sizes, int n_in,
                              void* d_out, int out_size, void* d_ws, size_t ws_size,
                              hipStream_t stream) {
  const float* x  = (const float*)d_in[0];
  const float* w  = (const float*)d_in[1];
  const float* br = (const float*)d_in[2];
  const float* wc = (const float*)d_in[3];
  const float* bc = (const float*)d_in[4];
  float* ws = (float*)d_ws;
  float* out = (float*)d_out;
  (void)in_sizes; (void)n_in; (void)out_size; (void)ws_size;

  k_prep<<<256, 256, 0, stream>>>(w, br, wc, bc, ws);
  k_r<<<1024, 256, 0, stream>>>(x, ws);
  k_s<<<2048, 256, 0, stream>>>(wc, ws);
  k_main<<<512, 256, 0, stream>>>(ws);
  k_epi<<<2048, 256, 0, stream>>>(br, ws, out);
}

// Round 2
// 132.769 us; speedup vs baseline: 2.6128x; 2.6128x over previous
//
#include <hip/hip_runtime.h>
#include <hip/hip_bf16.h>
#include <stdint.h>

#define NN 8192
#define CC 256
#define NSPLIT 8                          // j-splits; h = blk&7 -> per-XCD L2 locality

typedef float f32x4 __attribute__((ext_vector_type(4)));
typedef short s16x8 __attribute__((ext_vector_type(8)));

// ---- workspace layout (float offsets). Total ~46.7 MB. ----
#define OFF_WT  0                                 // 256*256 transposed w_reduce
#define OFF_R   (OFF_WT + CC*CC)                  // N*C fp32 r
#define OFF_S   (OFF_R + NN*CC)                   // N fp32 s
#define OFF_C0  (OFF_S + NN)                      // 1 fp32 c0 (padded 16)
#define OFF_SS  (OFF_C0 + 16)                     // NSPLIT*N fp32 partial row-sums of Z
#define OFF_V   (OFF_SS + NSPLIT*NN)              // NSPLIT*N*C bf16 partial Z@r (ushort)
#define OFF_RB  (OFF_V + (NSPLIT*NN*CC)/2)        // N*C bf16 (ushort) swizzled r

// ---------------- kernel 1: transpose Wr + compute c0 ----------------
__global__ __launch_bounds__(256) void k_prep(const float* __restrict__ w,
                                              const float* __restrict__ br,
                                              const float* __restrict__ wcv,
                                              const float* __restrict__ bc,
                                              float* __restrict__ ws) {
  int k = blockIdx.x, c = threadIdx.x;
  ws[OFF_WT + k * CC + c] = w[c * CC + k];   // wT[k][c] = w[c][k]
  if (blockIdx.x == 0 && threadIdx.x < 64) {
    int lane = threadIdx.x;
    f32x4 b4 = *(const f32x4*)&br[lane * 4];
    f32x4 w4 = *(const f32x4*)&wcv[lane * 4];
    float d = b4[0]*w4[0] + b4[1]*w4[1] + b4[2]*w4[2] + b4[3]*w4[3];
    #pragma unroll
    for (int m = 32; m >= 1; m >>= 1) d += __shfl_xor(d, m, 64);
    if (lane == 0) ws[OFF_C0] = d + bc[0];
  }
}

// ---------------- kernel 2: r = x @ Wr^T (fp32) + rb (bf16, B-frag order) ----
__global__ __launch_bounds__(256) void k_r(const float* __restrict__ x,
                                           float* __restrict__ ws) {
  __shared__ float xs[32][260];            // pad to kill bank conflicts
  int bi = blockIdx.x;                      // 1024 blocks
  int rowblk = bi >> 2, colblk = bi & 3;    // 32 rows x 64 cols per block
  int tid = threadIdx.x;
  int i0 = rowblk * 32;
  for (int t = tid; t < 32 * 64; t += 256) {
    int rr = t >> 6, c4 = t & 63;
    *(f32x4*)&xs[rr][c4 * 4] = *(const f32x4*)&x[(i0 + rr) * CC + c4 * 4];
  }
  __syncthreads();
  int tx = tid & 15, ty = tid >> 4;
  int cbase = colblk * 64 + tx * 4;
  float acc[2][4] = {};
  const float* wt = ws + OFF_WT;
  for (int k = 0; k < CC; k++) {
    f32x4 wv = *(const f32x4*)&wt[k * CC + cbase];
    float x0 = xs[ty * 2 + 0][k];
    float x1 = xs[ty * 2 + 1][k];
    #pragma unroll
    for (int cc = 0; cc < 4; cc++) {
      acc[0][cc] = fmaf(x0, wv[cc], acc[0][cc]);
      acc[1][cc] = fmaf(x1, wv[cc], acc[1][cc]);
    }
  }
  unsigned short* rb = (unsigned short*)(ws + OFF_RB);
  #pragma unroll
  for (int rr = 0; rr < 2; rr++) {
    int j = i0 + ty * 2 + rr;
    f32x4 o = {acc[rr][0], acc[rr][1], acc[rr][2], acc[rr][3]};
    *(f32x4*)&ws[OFF_R + j * CC + cbase] = o;
    #pragma unroll
    for (int cc = 0; cc < 4; cc++) {
      int c = cbase + cc;
      unsigned u = __float_as_uint(acc[rr][cc]);
      u = (u + 0x7fffu + ((u >> 16) & 1u)) >> 16;   // RNE to bf16
      // B-fragment order: lane l=(kk>>3)*16+(c&15) holds k-run t=kk&7 of chunk J
      int idx = (((j >> 5) * 16 + (c >> 4)) * 64 + ((j >> 3) & 3) * 16 + (c & 15)) * 8 + (j & 7);
      rb[idx] = (unsigned short)u;
    }
  }
}

// ---------------- kernel 3: s = r @ wc (wave per row) ----------------
__global__ __launch_bounds__(256) void k_s(const float* __restrict__ wcv,
                                           float* __restrict__ ws) {
  int tid = threadIdx.x;
  int lane = tid & 63;
  int row = blockIdx.x * 4 + (tid >> 6);
  f32x4 rv = *(const f32x4*)&ws[OFF_R + row * CC + lane * 4];
  f32x4 wv = *(const f32x4*)&wcv[lane * 4];
  float d = rv[0]*wv[0] + rv[1]*wv[1] + rv[2]*wv[2] + rv[3]*wv[3];
  #pragma unroll
  for (int m = 32; m >= 1; m >>= 1) d += __shfl_xor(d, m, 64);
  if (lane == 0) ws[OFF_S + row] = d;
}

// ---------------- kernel 4: main pairwise flash-style kernel ----------------
// 1024 blocks = 128 row-tiles (64 rows) x 8 j-splits (1024 j each), 4 waves/block.
// Register-double-buffered B-fragment loads: issue chunk t+1's 18 loads before
// chunk t's sigmoid+MFMA so L2 latency hides under compute.

#define LOADF(JB, BF, S0, S1) { \
  const float* sp_ = sarr + (JB) + g * 8; \
  S0 = *(const f32x4*)sp_; \
  S1 = *(const f32x4*)(sp_ + 4); \
  int Jb_ = ((JB) >> 5) * 16; \
  _Pragma("unroll") \
  for (int ct_ = 0; ct_ < 16; ct_++) BF[ct_] = rbs[((Jb_ + ct_) << 6) + l]; }

#define PHASE(BF, S0, S1) { \
  s16x8 af_; \
  _Pragma("unroll") \
  for (int t_ = 0; t_ < 8; t_++) { \
    float sj_ = (t_ < 4) ? (S0)[t_] : (S1)[t_ - 4]; \
    float e_ = __expf(nega - sj_); \
    float z_ = __builtin_amdgcn_rcpf(1.0f + e_); \
    ssum += z_; \
    unsigned u_ = __float_as_uint(z_); \
    u_ = (u_ + 0x7fffu + ((u_ >> 16) & 1u)) >> 16; \
    af_[t_] = (short)u_; } \
  _Pragma("unroll") \
  for (int ct_ = 0; ct_ < 16; ct_++) \
    acc[ct_] = __builtin_amdgcn_mfma_f32_16x16x32_bf16(af_, BF[ct_], acc[ct_], 0, 0, 0); }

__global__ __launch_bounds__(256) void k_main(float* __restrict__ ws) {
  int blk = blockIdx.x;
  int rt = blk >> 3, h = blk & 7;            // h == XCD id -> per-XCD L2 locality
  int tid = threadIdx.x;
  int w = tid >> 6, l = tid & 63;
  int lr = l & 15, g = l >> 4;
  int iw = rt * 64 + w * 16;                 // this wave's 16-row strip
  float c0v = ws[OFF_C0];
  float si = ws[OFF_S + iw + lr];
  float nega = -(si + c0v);                  // sigmoid = 1/(1+exp(nega - s_j))
  f32x4 acc[16];
  #pragma unroll
  for (int i = 0; i < 16; i++) acc[i] = (f32x4)(0.f);
  float ssum = 0.f;
  const s16x8* rbs = (const s16x8*)(ws + OFF_RB);
  const float* sarr = ws + OFF_S;
  const int JR = NN / NSPLIT;                // 1024
  const int NITER = JR / 32;                 // 32 (even)
  int j0 = h * JR;

  f32x4 sA0, sA1, sB0, sB1;
  s16x8 bfA[16], bfB[16];
  LOADF(j0, bfA, sA0, sA1);                  // prologue
  for (int it = 0; it < NITER; it += 2) {
    int jb = j0 + (it << 5);
    LOADF(jb + 32, bfB, sB0, sB1);           // prefetch t+1
    PHASE(bfA, sA0, sA1);                    // compute t
    int jn = (it + 2 < NITER) ? jb + 64 : jb + 32;  // clamp last (dummy reload)
    LOADF(jn, bfA, sA0, sA1);                // prefetch t+2
    PHASE(bfB, sB0, sB1);                    // compute t+1
  }

  // row-sums of Z: lanes {l, l+16, l+32, l+48} share row lr
  ssum += __shfl_xor(ssum, 16, 64);
  ssum += __shfl_xor(ssum, 32, 64);
  if (l < 16) ws[OFF_SS + h * NN + iw + l] = ssum;
  // C/D layout: col = lane&15, row = (lane>>4)*4 + reg  [measured m89/m91]
  unsigned short* Vb = (unsigned short*)(ws + OFF_V);
  size_t vbase = (size_t)h * (NN * CC);
  #pragma unroll
  for (int ct = 0; ct < 16; ct++) {
    #pragma unroll
    for (int q = 0; q < 4; q++) {
      unsigned u = __float_as_uint(acc[ct][q]);
      u = (u + 0x7fffu + ((u >> 16) & 1u)) >> 16;   // RNE to bf16
      Vb[vbase + (size_t)(iw + g * 4 + q) * CC + ct * 16 + lr] = (unsigned short)u;
    }
  }
}

// ---------------- kernel 5: epilogue out = (r+b)*S/N + sum_h V_h/N ----------
__global__ __launch_bounds__(256) void k_epi(const float* __restrict__ br,
                                             const float* __restrict__ ws,
                                             float* __restrict__ out) {
  int idx = blockIdx.x * 256 + threadIdx.x;   // N*C/8 = 262144 threads
  int i = idx >> 5, c8 = (idx & 31) * 8;
  float S = 0.f;
  #pragma unroll
  for (int p = 0; p < NSPLIT; p++) S += ws[OFF_SS + p * NN + i];
  float m = S * (1.0f / NN);
  float v[8] = {};
  const unsigned short* Vb = (const unsigned short*)(ws + OFF_V);
  #pragma unroll
  for (int p = 0; p < NSPLIT; p++) {
    s16x8 pv = *(const s16x8*)&Vb[(size_t)p * (NN * CC) + (size_t)i * CC + c8];
    #pragma unroll
    for (int t = 0; t < 8; t++)
      v[t] += __uint_as_float(((unsigned)(unsigned short)pv[t]) << 16);
  }
  f32x4 r0 = *(const f32x4*)&ws[OFF_R + (size_t)i * CC + c8];
  f32x4 r1 = *(const f32x4*)&ws[OFF_R + (size_t)i * CC + c8 + 4];
  f32x4 b0 = *(const f32x4*)&br[c8];
  f32x4 b1 = *(const f32x4*)&br[c8 + 4];
  f32x4 o0, o1;
  #pragma unroll
  for (int t = 0; t < 4; t++) {
    o0[t] = (r0[t] + b0[t]) * m + v[t] * (1.0f / NN);
    o1[t] = (r1[t] + b1[t]) * m + v[t + 4] * (1.0f / NN);
  }
  *(f32x4*)&out[(size_t)i * CC + c8] = o0;
  *(f32x4*)&out[(size_t)i * CC + c8 + 4] = o1;
}

extern "C" void kernel_launch(void* const* d_in, const int* in_sizes, int n_in,
                              void* d_out, int out_size, void* d_ws, size_t ws_size,
                              hipStream_t stream) {
  const float* x  = (const float*)d_in[0];
  const float* w  = (const float*)d_in[1];
  const float* br = (const float*)d_in[2];
  const float* wc = (const float*)d_in[3];
  const float* bc = (const float*)d_in[4];
  float* ws = (float*)d_ws;
  float* out = (float*)d_out;
  (void)in_sizes; (void)n_in; (void)out_size; (void)ws_size;

  k_prep<<<256, 256, 0, stream>>>(w, br, wc, bc, ws);
  k_r<<<1024, 256, 0, stream>>>(x, ws);
  k_s<<<2048, 256, 0, stream>>>(wc, ws);
  k_main<<<1024, 256, 0, stream>>>(ws);
  k_epi<<<1024, 256, 0, stream>>>(br, ws, out);
}

// Round 3
// 106.100 us; speedup vs baseline: 3.2695x; 1.2514x over previous
//
#include <hip/hip_runtime.h>
#include <hip/hip_bf16.h>
#include <stdint.h>

#define NN 8192
#define CC 256
#define NSPLIT 8                          // j-splits; h = blk&7 == XCD id
#define JR (NN / NSPLIT)                  // 1024 j per split
#define NITER (JR / 32)                   // 32 chunks of 32 j

typedef float f32x4 __attribute__((ext_vector_type(4)));
typedef short s16x8 __attribute__((ext_vector_type(8)));

#define LOG2E 1.4426950408889634f

// ---- workspace layout (float offsets). Total ~46.2 MB. ----
#define OFF_WT  0                                 // 256*256 transposed w_reduce
#define OFF_R   (OFF_WT + CC*CC)                  // N*C fp32 r
#define OFF_S2  (OFF_R + NN*CC)                   // N fp32 s*log2e
#define OFF_C0  (OFF_S2 + NN)                     // [0]=c0, [1]=c0*log2e
#define OFF_SS  (OFF_C0 + 16)                     // NSPLIT*N fp32 partial row-sums of Z
#define OFF_V   (OFF_SS + NSPLIT*NN)              // NSPLIT*N*C bf16 partial Z@r (ushort)
#define OFF_RB  (OFF_V + (NSPLIT*NN*CC)/2)        // N*C bf16 (ushort) fragment-ordered r

// ---------------- kernel 1: transpose Wr + compute c0 ----------------
__global__ __launch_bounds__(256) void k_prep(const float* __restrict__ w,
                                              const float* __restrict__ br,
                                              const float* __restrict__ wcv,
                                              const float* __restrict__ bc,
                                              float* __restrict__ ws) {
  int k = blockIdx.x, c = threadIdx.x;
  ws[OFF_WT + k * CC + c] = w[c * CC + k];   // wT[k][c] = w[c][k]
  if (blockIdx.x == 0 && threadIdx.x < 64) {
    int lane = threadIdx.x;
    f32x4 b4 = *(const f32x4*)&br[lane * 4];
    f32x4 w4 = *(const f32x4*)&wcv[lane * 4];
    float d = b4[0]*w4[0] + b4[1]*w4[1] + b4[2]*w4[2] + b4[3]*w4[3];
    #pragma unroll
    for (int m = 32; m >= 1; m >>= 1) d += __shfl_xor(d, m, 64);
    if (lane == 0) { ws[OFF_C0] = d + bc[0]; ws[OFF_C0 + 1] = (d + bc[0]) * LOG2E; }
  }
}

// ---------------- kernel 2: r = x @ Wr^T (fp32) + rb (bf16, B-frag order) ----
__global__ __launch_bounds__(256) void k_r(const float* __restrict__ x,
                                           float* __restrict__ ws) {
  __shared__ float xs[32][260];
  int bi = blockIdx.x;                      // 1024 blocks
  int rowblk = bi >> 2, colblk = bi & 3;    // 32 rows x 64 cols per block
  int tid = threadIdx.x;
  int i0 = rowblk * 32;
  for (int t = tid; t < 32 * 64; t += 256) {
    int rr = t >> 6, c4 = t & 63;
    *(f32x4*)&xs[rr][c4 * 4] = *(const f32x4*)&x[(i0 + rr) * CC + c4 * 4];
  }
  __syncthreads();
  int tx = tid & 15, ty = tid >> 4;
  int cbase = colblk * 64 + tx * 4;
  float acc[2][4] = {};
  const float* wt = ws + OFF_WT;
  for (int k = 0; k < CC; k++) {
    f32x4 wv = *(const f32x4*)&wt[k * CC + cbase];
    float x0 = xs[ty * 2 + 0][k];
    float x1 = xs[ty * 2 + 1][k];
    #pragma unroll
    for (int cc = 0; cc < 4; cc++) {
      acc[0][cc] = fmaf(x0, wv[cc], acc[0][cc]);
      acc[1][cc] = fmaf(x1, wv[cc], acc[1][cc]);
    }
  }
  unsigned short* rb = (unsigned short*)(ws + OFF_RB);
  #pragma unroll
  for (int rr = 0; rr < 2; rr++) {
    int j = i0 + ty * 2 + rr;
    f32x4 o = {acc[rr][0], acc[rr][1], acc[rr][2], acc[rr][3]};
    *(f32x4*)&ws[OFF_R + j * CC + cbase] = o;
    #pragma unroll
    for (int cc = 0; cc < 4; cc++) {
      int c = cbase + cc;
      unsigned u = __float_as_uint(acc[rr][cc]);
      u = (u + 0x7fffu + ((u >> 16) & 1u)) >> 16;   // RNE to bf16
      // fragment order: chunk (j>>5), col-frag (c>>4), lane ((j>>3)&3)*16+(c&15), k-run (j&7)
      int idx = (((j >> 5) * 16 + (c >> 4)) * 64 + ((j >> 3) & 3) * 16 + (c & 15)) * 8 + (j & 7);
      rb[idx] = (unsigned short)u;
    }
  }
}

// ---------------- kernel 3: s2 = (r @ wc) * log2e (wave per row) ----------------
__global__ __launch_bounds__(256) void k_s(const float* __restrict__ wcv,
                                           float* __restrict__ ws) {
  int tid = threadIdx.x;
  int lane = tid & 63;
  int row = blockIdx.x * 4 + (tid >> 6);
  f32x4 rv = *(const f32x4*)&ws[OFF_R + row * CC + lane * 4];
  f32x4 wv = *(const f32x4*)&wcv[lane * 4];
  float d = rv[0]*wv[0] + rv[1]*wv[1] + rv[2]*wv[2] + rv[3]*wv[3];
  #pragma unroll
  for (int m = 32; m >= 1; m >>= 1) d += __shfl_xor(d, m, 64);
  if (lane == 0) ws[OFF_S2 + row] = d * LOG2E;
}

// ---------------- kernel 4: main pairwise flash-style kernel ----------------
// 512 blocks = 64 row-tiles (128 rows) x 8 j-splits (1024 j each), 4 waves/block.
// B tile LDS-staged once per block (global_load_lds w16, 2x16KB double buffer);
// each wave computes 32 rows (2 A-fragments) -> L2 traffic 268 MB total.

#define STAGE(BUF, IT) { \
  const char* gb_ = rbase + (size_t)(IT) * 16384 + w * 1024 + l * 16; \
  _Pragma("unroll") \
  for (int q_ = 0; q_ < 4; q_++) \
    __builtin_amdgcn_global_load_lds( \
      (const __attribute__((address_space(1))) void*)(gb_ + q_ * 4096), \
      (__attribute__((address_space(3))) void*)&lds[BUF][w * 1024 + q_ * 4096], \
      16, 0, 0); }

__global__ __launch_bounds__(256, 2) void k_main(float* __restrict__ ws) {
  __shared__ char lds[2][16384];
  int blk = blockIdx.x;
  int rt = blk >> 3, h = blk & 7;            // h == XCD id -> per-XCD L2 locality
  int tid = threadIdx.x;
  int w = tid >> 6, l = tid & 63;
  int lr = l & 15, g = l >> 4;
  int iw = rt * 128 + w * 32;                // wave's 32-row strip (2 frags of 16)
  float c02 = ws[OFF_C0 + 1];
  float negaA = -(ws[OFF_S2 + iw + lr] + c02);
  float negaB = -(ws[OFF_S2 + iw + 16 + lr] + c02);
  f32x4 accA[16], accB[16], acc1A, acc1B;
  #pragma unroll
  for (int i = 0; i < 16; i++) { accA[i] = (f32x4)(0.f); accB[i] = (f32x4)(0.f); }
  acc1A = (f32x4)(0.f); acc1B = (f32x4)(0.f);
  s16x8 ones;
  #pragma unroll
  for (int t = 0; t < 8; t++) ones[t] = (short)0x3F80;   // bf16 1.0

  const char* rbase = (const char*)(ws + OFF_RB) + (size_t)h * (JR * CC * 2);
  const float* s2p = ws + OFF_S2 + h * JR;

  STAGE(0, 0);
  for (int it = 0; it < NITER; ++it) {
    __syncthreads();                        // drains vmcnt+lgkm: staged buf ready
    if (it + 1 < NITER) STAGE((it + 1) & 1, it + 1);
    // --- sigmoids for 2 row-fragments x 8 j (VALU, overlaps staging) ---
    f32x4 sj0 = *(const f32x4*)(s2p + it * 32 + g * 8);
    f32x4 sj1 = *(const f32x4*)(s2p + it * 32 + g * 8 + 4);
    s16x8 afA, afB;
    #pragma unroll
    for (int t = 0; t < 8; t++) {
      float sj = (t < 4) ? sj0[t] : sj1[t - 4];
      float eA, eB;
      asm("v_exp_f32 %0, %1" : "=v"(eA) : "v"(negaA - sj));
      asm("v_exp_f32 %0, %1" : "=v"(eB) : "v"(negaB - sj));
      float zA = __builtin_amdgcn_rcpf(1.0f + eA);
      float zB = __builtin_amdgcn_rcpf(1.0f + eB);
      unsigned uA = __float_as_uint(zA);
      uA = (uA + 0x7fffu + ((uA >> 16) & 1u)) >> 16;
      afA[t] = (short)uA;
      unsigned uB = __float_as_uint(zB);
      uB = (uB + 0x7fffu + ((uB >> 16) & 1u)) >> 16;
      afB[t] = (short)uB;
    }
    // --- MFMA against LDS-staged B fragments ---
    const char* lp = lds[it & 1];
    #pragma unroll
    for (int ct = 0; ct < 16; ct++) {
      s16x8 bf = *(const s16x8*)(lp + ct * 1024 + l * 16);   // ds_read_b128, conflict-free
      accA[ct] = __builtin_amdgcn_mfma_f32_16x16x32_bf16(afA, bf, accA[ct], 0, 0, 0);
      accB[ct] = __builtin_amdgcn_mfma_f32_16x16x32_bf16(afB, bf, accB[ct], 0, 0, 0);
    }
    acc1A = __builtin_amdgcn_mfma_f32_16x16x32_bf16(afA, ones, acc1A, 0, 0, 0);
    acc1B = __builtin_amdgcn_mfma_f32_16x16x32_bf16(afB, ones, acc1B, 0, 0, 0);
  }

  // row-sums of Z from ones-MFMA: all cols equal; col-0 lanes (lr==0) write 4 rows each
  if (lr == 0) {
    #pragma unroll
    for (int q = 0; q < 4; q++) {
      ws[OFF_SS + h * NN + iw + g * 4 + q] = acc1A[q];
      ws[OFF_SS + h * NN + iw + 16 + g * 4 + q] = acc1B[q];
    }
  }
  // V partials (bf16). C/D layout: col = lane&15, row = (lane>>4)*4 + reg
  unsigned short* Vb = (unsigned short*)(ws + OFF_V);
  size_t vbase = (size_t)h * (NN * CC);
  #pragma unroll
  for (int ct = 0; ct < 16; ct++) {
    #pragma unroll
    for (int q = 0; q < 4; q++) {
      unsigned uA = __float_as_uint(accA[ct][q]);
      uA = (uA + 0x7fffu + ((uA >> 16) & 1u)) >> 16;
      Vb[vbase + (size_t)(iw + g * 4 + q) * CC + ct * 16 + lr] = (unsigned short)uA;
      unsigned uB = __float_as_uint(accB[ct][q]);
      uB = (uB + 0x7fffu + ((uB >> 16) & 1u)) >> 16;
      Vb[vbase + (size_t)(iw + 16 + g * 4 + q) * CC + ct * 16 + lr] = (unsigned short)uB;
    }
  }
}

// ---------------- kernel 5: epilogue out = (r+b)*S/N + sum_h V_h/N ----------
__global__ __launch_bounds__(256) void k_epi(const float* __restrict__ br,
                                             const float* __restrict__ ws,
                                             float* __restrict__ out) {
  int idx = blockIdx.x * 256 + threadIdx.x;   // N*C/8 = 262144 threads
  int i = idx >> 5, c8 = (idx & 31) * 8;
  float S = 0.f;
  #pragma unroll
  for (int p = 0; p < NSPLIT; p++) S += ws[OFF_SS + p * NN + i];
  float m = S * (1.0f / NN);
  float v[8] = {};
  const unsigned short* Vb = (const unsigned short*)(ws + OFF_V);
  #pragma unroll
  for (int p = 0; p < NSPLIT; p++) {
    s16x8 pv = *(const s16x8*)&Vb[(size_t)p * (NN * CC) + (size_t)i * CC + c8];
    #pragma unroll
    for (int t = 0; t < 8; t++)
      v[t] += __uint_as_float(((unsigned)(unsigned short)pv[t]) << 16);
  }
  f32x4 r0 = *(const f32x4*)&ws[OFF_R + (size_t)i * CC + c8];
  f32x4 r1 = *(const f32x4*)&ws[OFF_R + (size_t)i * CC + c8 + 4];
  f32x4 b0 = *(const f32x4*)&br[c8];
  f32x4 b1 = *(const f32x4*)&br[c8 + 4];
  f32x4 o0, o1;
  #pragma unroll
  for (int t = 0; t < 4; t++) {
    o0[t] = (r0[t] + b0[t]) * m + v[t] * (1.0f / NN);
    o1[t] = (r1[t] + b1[t]) * m + v[t + 4] * (1.0f / NN);
  }
  *(f32x4*)&out[(size_t)i * CC + c8] = o0;
  *(f32x4*)&out[(size_t)i * CC + c8 + 4] = o1;
}

extern "C" void kernel_launch(void* const* d_in, const int* in_sizes, int n_in,
                              void* d_out, int out_size, void* d_ws, size_t ws_size,
                              hipStream_t stream) {
  const float* x  = (const float*)d_in[0];
  const float* w  = (const float*)d_in[1];
  const float* br = (const float*)d_in[2];
  const float* wc = (const float*)d_in[3];
  const float* bc = (const float*)d_in[4];
  float* ws = (float*)d_ws;
  float* out = (float*)d_out;
  (void)in_sizes; (void)n_in; (void)out_size; (void)ws_size;

  k_prep<<<256, 256, 0, stream>>>(w, br, wc, bc, ws);
  k_r<<<1024, 256, 0, stream>>>(x, ws);
  k_s<<<2048, 256, 0, stream>>>(wc, ws);
  k_main<<<512, 256, 0, stream>>>(ws);
  k_epi<<<1024, 256, 0, stream>>>(br, ws, out);
}

// Round 4
// 93.766 us; speedup vs baseline: 3.6996x; 1.1315x over previous
//
#include <hip/hip_runtime.h>
#include <hip/hip_bf16.h>
#include <stdint.h>

#define NN 8192
#define CC 256
#define NSPLIT 8                          // j-splits; h = blk&7 == XCD id
#define JR (NN / NSPLIT)                  // 1024 j per split
#define NITER (JR / 32)                   // 32 chunks of 32 j

typedef float f32x4 __attribute__((ext_vector_type(4)));
typedef float f32x2 __attribute__((ext_vector_type(2)));
typedef short s16x8 __attribute__((ext_vector_type(8)));

#define LOG2E 1.4426950408889634f

// ---- workspace layout (float offsets). Total ~46.2 MB. ----
#define OFF_WT  0                                 // 256*256 transposed w_reduce
#define OFF_R   (OFF_WT + CC*CC)                  // N*C fp32 r
#define OFF_S2  (OFF_R + NN*CC)                   // N fp32 s*log2e
#define OFF_C0  (OFF_S2 + NN)                     // [0]=c0, [1]=c0*log2e
#define OFF_SS  (OFF_C0 + 16)                     // NSPLIT*N fp32 partial row-sums of Z
#define OFF_V   (OFF_SS + NSPLIT*NN)              // NSPLIT*N*C bf16 partial Z@r (ushort)
#define OFF_RB  (OFF_V + (NSPLIT*NN*CC)/2)        // N*C bf16 (ushort) fragment-ordered r

// ---------------- kernel 1: transpose Wr + compute c0 ----------------
__global__ __launch_bounds__(256) void k_prep(const float* __restrict__ w,
                                              const float* __restrict__ br,
                                              const float* __restrict__ wcv,
                                              const float* __restrict__ bc,
                                              float* __restrict__ ws) {
  int k = blockIdx.x, c = threadIdx.x;
  ws[OFF_WT + k * CC + c] = w[c * CC + k];   // wT[k][c] = w[c][k]
  if (blockIdx.x == 0 && threadIdx.x < 64) {
    int lane = threadIdx.x;
    f32x4 b4 = *(const f32x4*)&br[lane * 4];
    f32x4 w4 = *(const f32x4*)&wcv[lane * 4];
    float d = b4[0]*w4[0] + b4[1]*w4[1] + b4[2]*w4[2] + b4[3]*w4[3];
    #pragma unroll
    for (int m = 32; m >= 1; m >>= 1) d += __shfl_xor(d, m, 64);
    if (lane == 0) { ws[OFF_C0] = d + bc[0]; ws[OFF_C0 + 1] = (d + bc[0]) * LOG2E; }
  }
}

// ---------------- kernel 2: r = x @ Wr^T (fp32) + rb (bf16, B-frag order) ----
// 512 blocks: 64 rows x 64 cols per block, 4x4 per thread, k-unroll-2.
__global__ __launch_bounds__(256) void k_r(const float* __restrict__ x,
                                           float* __restrict__ ws) {
  __shared__ float xs[64][260];
  int bi = blockIdx.x;
  int rowblk = bi >> 2, colblk = bi & 3;
  int tid = threadIdx.x;
  int i0 = rowblk * 64;
  for (int t = tid; t < 64 * 64; t += 256) {
    int rr = t >> 6, c4 = t & 63;
    *(f32x4*)&xs[rr][c4 * 4] = *(const f32x4*)&x[(i0 + rr) * CC + c4 * 4];
  }
  __syncthreads();
  int tx = tid & 15, ty = tid >> 4;
  int cbase = colblk * 64 + tx * 4;
  int r0 = ty * 4;
  float acc[4][4] = {};
  const float* wt = ws + OFF_WT;
  for (int k = 0; k < CC; k += 2) {
    f32x4 wv0 = *(const f32x4*)&wt[k * CC + cbase];
    f32x4 wv1 = *(const f32x4*)&wt[(k + 1) * CC + cbase];
    f32x2 xv[4];
    #pragma unroll
    for (int rr = 0; rr < 4; rr++) xv[rr] = *(const f32x2*)&xs[r0 + rr][k];
    #pragma unroll
    for (int rr = 0; rr < 4; rr++)
      #pragma unroll
      for (int cc = 0; cc < 4; cc++)
        acc[rr][cc] = fmaf(xv[rr][1], wv1[cc], fmaf(xv[rr][0], wv0[cc], acc[rr][cc]));
  }
  unsigned short* rb = (unsigned short*)(ws + OFF_RB);
  #pragma unroll
  for (int rr = 0; rr < 4; rr++) {
    int j = i0 + r0 + rr;
    f32x4 o = {acc[rr][0], acc[rr][1], acc[rr][2], acc[rr][3]};
    *(f32x4*)&ws[OFF_R + j * CC + cbase] = o;
    #pragma unroll
    for (int cc = 0; cc < 4; cc++) {
      int c = cbase + cc;
      unsigned u = __float_as_uint(acc[rr][cc]);
      u = (u + 0x7fffu + ((u >> 16) & 1u)) >> 16;   // RNE to bf16
      int idx = (((j >> 5) * 16 + (c >> 4)) * 64 + ((j >> 3) & 3) * 16 + (c & 15)) * 8 + (j & 7);
      rb[idx] = (unsigned short)u;
    }
  }
}

// ---------------- kernel 3: s2 = (r @ wc) * log2e (wave per row) ----------------
__global__ __launch_bounds__(256) void k_s(const float* __restrict__ wcv,
                                           float* __restrict__ ws) {
  int tid = threadIdx.x;
  int lane = tid & 63;
  int row = blockIdx.x * 4 + (tid >> 6);
  f32x4 rv = *(const f32x4*)&ws[OFF_R + row * CC + lane * 4];
  f32x4 wv = *(const f32x4*)&wcv[lane * 4];
  float d = rv[0]*wv[0] + rv[1]*wv[1] + rv[2]*wv[2] + rv[3]*wv[3];
  #pragma unroll
  for (int m = 32; m >= 1; m >>= 1) d += __shfl_xor(d, m, 64);
  if (lane == 0) ws[OFF_S2 + row] = d * LOG2E;
}

// ---------------- kernel 4: main pairwise flash-style kernel ----------------
// 512 blocks = 64 row-tiles (128 rows) x 8 j-splits, 4 waves/block.
// 3-buffer depth-2 pipeline: counted s_waitcnt vmcnt(4), raw s_barrier.
// Only VMEM in the loop is global_load_lds -> our waits own vmcnt.

#define STAGE(BUF, IT) { \
  const char* gb_ = rbase + (size_t)(IT) * 16384 + w * 1024 + l * 16; \
  _Pragma("unroll") \
  for (int q_ = 0; q_ < 4; q_++) \
    __builtin_amdgcn_global_load_lds( \
      (const __attribute__((address_space(1))) void*)(gb_ + q_ * 4096), \
      (__attribute__((address_space(3))) void*)&ldsb[(BUF) * 16384 + w * 1024 + q_ * 4096], \
      16, 0, 0); }

#define WAITBAR4 { asm volatile("s_waitcnt vmcnt(4)" ::: "memory"); \
  __builtin_amdgcn_s_barrier(); \
  __builtin_amdgcn_sched_barrier(0); }

#define WAITBAR0 { asm volatile("s_waitcnt vmcnt(0)" ::: "memory"); \
  __builtin_amdgcn_s_barrier(); \
  __builtin_amdgcn_sched_barrier(0); }

#define SIGMOID(IT, AFA, AFB) { \
  f32x4 sj0_ = *(const f32x4*)&s2l[(IT) * 32 + g * 8]; \
  f32x4 sj1_ = *(const f32x4*)&s2l[(IT) * 32 + g * 8 + 4]; \
  _Pragma("unroll") \
  for (int t_ = 0; t_ < 8; t_++) { \
    float sj_ = (t_ < 4) ? sj0_[t_] : sj1_[t_ - 4]; \
    float eA_, eB_; \
    asm("v_exp_f32 %0, %1" : "=v"(eA_) : "v"(negaA - sj_)); \
    asm("v_exp_f32 %0, %1" : "=v"(eB_) : "v"(negaB - sj_)); \
    float zA_ = __builtin_amdgcn_rcpf(1.0f + eA_); \
    float zB_ = __builtin_amdgcn_rcpf(1.0f + eB_); \
    unsigned uA_ = __float_as_uint(zA_); \
    uA_ = (uA_ + 0x7fffu + ((uA_ >> 16) & 1u)) >> 16; \
    (AFA)[t_] = (short)uA_; \
    unsigned uB_ = __float_as_uint(zB_); \
    uB_ = (uB_ + 0x7fffu + ((uB_ >> 16) & 1u)) >> 16; \
    (AFB)[t_] = (short)uB_; } }

#define MFMA_PHASE(AFA, AFB, LP) { \
  __builtin_amdgcn_s_setprio(1); \
  _Pragma("unroll") \
  for (int ct_ = 0; ct_ < 16; ct_++) { \
    s16x8 bf_ = *(const s16x8*)((LP) + ct_ * 1024 + l * 16); \
    accA[ct_] = __builtin_amdgcn_mfma_f32_16x16x32_bf16(AFA, bf_, accA[ct_], 0, 0, 0); \
    accB[ct_] = __builtin_amdgcn_mfma_f32_16x16x32_bf16(AFB, bf_, accB[ct_], 0, 0, 0); } \
  acc1A = __builtin_amdgcn_mfma_f32_16x16x32_bf16(AFA, ones, acc1A, 0, 0, 0); \
  acc1B = __builtin_amdgcn_mfma_f32_16x16x32_bf16(AFB, ones, acc1B, 0, 0, 0); \
  __builtin_amdgcn_s_setprio(0); }

__global__ __launch_bounds__(256, 2) void k_main(float* __restrict__ ws) {
  __shared__ char ldsb[3 * 16384];
  __shared__ float s2l[1024];
  int blk = blockIdx.x;
  int rt = blk >> 3, h = blk & 7;            // h == XCD id -> per-XCD L2 locality
  int tid = threadIdx.x;
  int w = tid >> 6, l = tid & 63;
  int lr = l & 15, g = l >> 4;
  int iw = rt * 128 + w * 32;                // wave's 32-row strip (2 frags of 16)
  float c02 = ws[OFF_C0 + 1];
  float negaA = -(ws[OFF_S2 + iw + lr] + c02);
  float negaB = -(ws[OFF_S2 + iw + 16 + lr] + c02);

  // stage this split's s2 slice to LDS (keeps loop VMEM = global_load_lds only)
  const float* s2p = ws + OFF_S2 + h * JR;
  *(f32x4*)&s2l[tid * 4] = *(const f32x4*)(s2p + tid * 4);
  __syncthreads();

  f32x4 accA[16], accB[16], acc1A, acc1B;
  #pragma unroll
  for (int i = 0; i < 16; i++) { accA[i] = (f32x4)(0.f); accB[i] = (f32x4)(0.f); }
  acc1A = (f32x4)(0.f); acc1B = (f32x4)(0.f);
  s16x8 ones;
  #pragma unroll
  for (int t = 0; t < 8; t++) ones[t] = (short)0x3F80;   // bf16 1.0

  const char* rbase = (const char*)(ws + OFF_RB) + (size_t)h * (JR * CC * 2);

  STAGE(0, 0);
  STAGE(1, 1);
  s16x8 afA0, afB0, afA1, afB1;
  SIGMOID(0, afA0, afB0);

  for (int it = 0; it < NITER - 2; it += 2) {
    const char* lp0 = ldsb + (it % 3) * 16384;
    SIGMOID(it + 1, afA1, afB1);             // VALU fills the wait slot
    WAITBAR4;
    STAGE((it + 2) % 3, it + 2);
    MFMA_PHASE(afA0, afB0, lp0);
    const char* lp1 = ldsb + ((it + 1) % 3) * 16384;
    SIGMOID(it + 2, afA0, afB0);
    WAITBAR4;
    STAGE((it + 3) % 3, it + 3);
    MFMA_PHASE(afA1, afB1, lp1);
  }
  {                                          // J = NITER-2 (no stage left)
    const char* lp = ldsb + ((NITER - 2) % 3) * 16384;
    SIGMOID(NITER - 1, afA1, afB1);
    WAITBAR4;
    MFMA_PHASE(afA0, afB0, lp);
  }
  {                                          // J = NITER-1
    const char* lp = ldsb + ((NITER - 1) % 3) * 16384;
    WAITBAR0;
    MFMA_PHASE(afA1, afB1, lp);
  }

  // row-sums of Z from ones-MFMA (all cols equal; lr==0 lanes write 4 rows each)
  if (lr == 0) {
    #pragma unroll
    for (int q = 0; q < 4; q++) {
      ws[OFF_SS + h * NN + iw + g * 4 + q] = acc1A[q];
      ws[OFF_SS + h * NN + iw + 16 + g * 4 + q] = acc1B[q];
    }
  }
  // V partials (bf16). C/D layout: col = lane&15, row = (lane>>4)*4 + reg
  unsigned short* Vb = (unsigned short*)(ws + OFF_V);
  size_t vbase = (size_t)h * (NN * CC);
  #pragma unroll
  for (int ct = 0; ct < 16; ct++) {
    #pragma unroll
    for (int q = 0; q < 4; q++) {
      unsigned uA = __float_as_uint(accA[ct][q]);
      uA = (uA + 0x7fffu + ((uA >> 16) & 1u)) >> 16;
      Vb[vbase + (size_t)(iw + g * 4 + q) * CC + ct * 16 + lr] = (unsigned short)uA;
      unsigned uB = __float_as_uint(accB[ct][q]);
      uB = (uB + 0x7fffu + ((uB >> 16) & 1u)) >> 16;
      Vb[vbase + (size_t)(iw + 16 + g * 4 + q) * CC + ct * 16 + lr] = (unsigned short)uB;
    }
  }
}

// ---------------- kernel 5: epilogue out = (r+b)*S/N + sum_h V_h/N ----------
__global__ __launch_bounds__(256) void k_epi(const float* __restrict__ br,
                                             const float* __restrict__ ws,
                                             float* __restrict__ out) {
  int idx = blockIdx.x * 256 + threadIdx.x;   // N*C/8 = 262144 threads
  int i = idx >> 5, c8 = (idx & 31) * 8;
  float S = 0.f;
  #pragma unroll
  for (int p = 0; p < NSPLIT; p++) S += ws[OFF_SS + p * NN + i];
  float m = S * (1.0f / NN);
  float v[8] = {};
  const unsigned short* Vb = (const unsigned short*)(ws + OFF_V);
  #pragma unroll
  for (int p = 0; p < NSPLIT; p++) {
    s16x8 pv = *(const s16x8*)&Vb[(size_t)p * (NN * CC) + (size_t)i * CC + c8];
    #pragma unroll
    for (int t = 0; t < 8; t++)
      v[t] += __uint_as_float(((unsigned)(unsigned short)pv[t]) << 16);
  }
  f32x4 r0 = *(const f32x4*)&ws[OFF_R + (size_t)i * CC + c8];
  f32x4 r1 = *(const f32x4*)&ws[OFF_R + (size_t)i * CC + c8 + 4];
  f32x4 b0 = *(const f32x4*)&br[c8];
  f32x4 b1 = *(const f32x4*)&br[c8 + 4];
  f32x4 o0, o1;
  #pragma unroll
  for (int t = 0; t < 4; t++) {
    o0[t] = (r0[t] + b0[t]) * m + v[t] * (1.0f / NN);
    o1[t] = (r1[t] + b1[t]) * m + v[t + 4] * (1.0f / NN);
  }
  *(f32x4*)&out[(size_t)i * CC + c8] = o0;
  *(f32x4*)&out[(size_t)i * CC + c8 + 4] = o1;
}

extern "C" void kernel_launch(void* const* d_in, const int* in_sizes, int n_in,
                              void* d_out, int out_size, void* d_ws, size_t ws_size,
                              hipStream_t stream) {
  const float* x  = (const float*)d_in[0];
  const float* w  = (const float*)d_in[1];
  const float* br = (const float*)d_in[2];
  const float* wc = (const float*)d_in[3];
  const float* bc = (const float*)d_in[4];
  float* ws = (float*)d_ws;
  float* out = (float*)d_out;
  (void)in_sizes; (void)n_in; (void)out_size; (void)ws_size;

  k_prep<<<256, 256, 0, stream>>>(w, br, wc, bc, ws);
  k_r<<<512, 256, 0, stream>>>(x, ws);
  k_s<<<2048, 256, 0, stream>>>(wc, ws);
  k_main<<<512, 256, 0, stream>>>(ws);
  k_epi<<<1024, 256, 0, stream>>>(br, ws, out);
}